// Round 1
// baseline (207.764 us; speedup 1.0000x reference)
//
#include <hip/hip_runtime.h>

#define MNODES 384
#define RTHRESH 0.05f

// ---------------------------------------------------------------------------
// Workspace layout (bytes):
//   state : 1536*3 floats            @ 0        (18432 B)
//   cnt   : 1536 ints                @ 18432    (6144 B)
//   lists : 1536*384 u16             @ 24576    (1179648 B)
//   phi   : 1536*128 floats          @ 1204224  (786432 B)
// total ~1.99 MB
// ---------------------------------------------------------------------------

// Adjacency: one block per batch n, thread i scans all j. Neighbor lists in u16.
__global__ __launch_bounds__(384) void adj_kernel(const float* __restrict__ x,
                                                  int* __restrict__ cnt,
                                                  unsigned short* __restrict__ lists) {
    __shared__ float xs[MNODES * 3];
    const int n = blockIdx.x;
    const int i = threadIdx.x;
    for (int idx = threadIdx.x; idx < MNODES * 3; idx += blockDim.x)
        xs[idx] = x[n * MNODES * 3 + idx];
    __syncthreads();
    const float xi0 = xs[i * 3], xi1 = xs[i * 3 + 1], xi2 = xs[i * 3 + 2];
    unsigned short* ml = lists + (size_t)(n * MNODES + i) * MNODES;
    int c = 0;
    for (int j = 0; j < MNODES; ++j) {
        float dx = xs[j * 3] - xi0;
        float dy = xs[j * 3 + 1] - xi1;
        float dz = xs[j * 3 + 2] - xi2;
        // match numpy rounding exactly (no fp-contract): (dx*dx + dy*dy) + dz*dz
        float d2 = __fadd_rn(__fadd_rn(__fmul_rn(dx, dx), __fmul_rn(dy, dy)), __fmul_rn(dz, dz));
        if (d2 < RTHRESH) { ml[c++] = (unsigned short)j; }
    }
    cnt[n * MNODES + i] = c;
}

// phi[node][128] = relu(W3^T relu(W2^T relu(W1[3:6]^T s + b1) + b2) + b3)
// One 256-thread block handles 16 consecutive nodes (all within one batch: 384%16==0).
// Wave q handles nodes 4q..4q+3; lane kp handles neurons kp and kp+64.
__global__ __launch_bounds__(256) void phi_kernel(const float* __restrict__ state,
                                                  const float* __restrict__ fW1,
                                                  const float* __restrict__ fb1,
                                                  const float* __restrict__ fW2,
                                                  const float* __restrict__ fb2,
                                                  const float* __restrict__ fW3,
                                                  const float* __restrict__ fb3,
                                                  float* __restrict__ phi) {
    __shared__ __align__(16) float sA[16 * 3];
    __shared__ __align__(16) float H1T[64 * 16];   // [c][node_local]
    __shared__ __align__(16) float H2T[128 * 16];  // [c][node_local]
    const int tid = threadIdx.x;
    const int wgNode = blockIdx.x * 16;  // global node base (node = n*384+i)

    if (tid < 48) sA[tid] = state[wgNode * 3 + tid];
    __syncthreads();

    // Layer 1 (effective 3->64; rel slot is exactly zero so rows 0..2 of fW1 unused)
    for (int rep = 0; rep < 4; ++rep) {
        int idx = tid + rep * 256;
        int nl = idx >> 6, k = idx & 63;
        float v = fb1[k]
                + sA[nl * 3 + 0] * fW1[3 * 64 + k]
                + sA[nl * 3 + 1] * fW1[4 * 64 + k]
                + sA[nl * 3 + 2] * fW1[5 * 64 + k];
        H1T[k * 16 + nl] = fmaxf(v, 0.0f);
    }
    __syncthreads();

    const int q = tid >> 6, kp = tid & 63;

    // Layer 2: 64 -> 128
    {
        float acc[4][2];
        const float b0 = fb2[kp], b1 = fb2[kp + 64];
        for (int r = 0; r < 4; ++r) { acc[r][0] = b0; acc[r][1] = b1; }
        for (int c = 0; c < 64; ++c) {
            const float4 h = *(const float4*)&H1T[c * 16 + 4 * q];  // wave-broadcast
            const float w0 = fW2[c * 128 + kp];
            const float w1 = fW2[c * 128 + kp + 64];
            acc[0][0] += h.x * w0; acc[0][1] += h.x * w1;
            acc[1][0] += h.y * w0; acc[1][1] += h.y * w1;
            acc[2][0] += h.z * w0; acc[2][1] += h.z * w1;
            acc[3][0] += h.w * w0; acc[3][1] += h.w * w1;
        }
        for (int r = 0; r < 4; ++r) {
            H2T[kp * 16 + 4 * q + r]        = fmaxf(acc[r][0], 0.0f);
            H2T[(kp + 64) * 16 + 4 * q + r] = fmaxf(acc[r][1], 0.0f);
        }
    }
    __syncthreads();

    // Layer 3: 128 -> 128, final relu, write phi
    {
        float acc[4][2];
        const float b0 = fb3[kp], b1 = fb3[kp + 64];
        for (int r = 0; r < 4; ++r) { acc[r][0] = b0; acc[r][1] = b1; }
        for (int c = 0; c < 128; ++c) {
            const float4 h = *(const float4*)&H2T[c * 16 + 4 * q];
            const float w0 = fW3[c * 128 + kp];
            const float w1 = fW3[c * 128 + kp + 64];
            acc[0][0] += h.x * w0; acc[0][1] += h.x * w1;
            acc[1][0] += h.y * w0; acc[1][1] += h.y * w1;
            acc[2][0] += h.z * w0; acc[2][1] += h.z * w1;
            acc[3][0] += h.w * w0; acc[3][1] += h.w * w1;
        }
        for (int r = 0; r < 4; ++r) {
            const int node = wgNode + 4 * q + r;
            phi[node * 128 + kp]      = fmaxf(acc[r][0], 0.0f);
            phi[node * 128 + kp + 64] = fmaxf(acc[r][1], 0.0f);
        }
    }
}

// Fused agg (max over neighbor phi) + MLP_g + residual. One wave per node.
__global__ __launch_bounds__(256) void aggg_kernel(const float* __restrict__ phi,
                                                   const int* __restrict__ cnt,
                                                   const unsigned short* __restrict__ lists,
                                                   const float* __restrict__ statesrc,
                                                   const float* __restrict__ gW1,
                                                   const float* __restrict__ gb1,
                                                   const float* __restrict__ gW2,
                                                   const float* __restrict__ gb2,
                                                   const float* __restrict__ gW3,
                                                   const float* __restrict__ gb3,
                                                   float* __restrict__ dst) {
    __shared__ float aggL[4][128];
    __shared__ float h1L[4][64];
    __shared__ float h2L[4][32];
    const int tid = threadIdx.x;
    const int wv = tid >> 6, lane = tid & 63;
    const int node = blockIdx.x * 4 + wv;            // [0,1536)
    const int nbase = (node / MNODES) * MNODES;      // batch base node
    const int nc = cnt[node];
    const unsigned short* ml = lists + (size_t)node * MNODES;

    // agg: max over neighbors; phi >= 0 and masked entries are 0, so init 0 is exact
    float a0 = 0.0f, a1 = 0.0f;
    for (int jj = 0; jj < nc; ++jj) {
        const int j = ml[jj];
        const float* pr = phi + (size_t)(nbase + j) * 128;
        a0 = fmaxf(a0, pr[lane]);
        a1 = fmaxf(a1, pr[lane + 64]);
    }
    aggL[wv][lane] = a0;
    aggL[wv][lane + 64] = a1;
    __syncthreads();

    // g1: 128 -> 64
    float h = gb1[lane];
    for (int c = 0; c < 128; ++c) h += aggL[wv][c] * gW1[c * 64 + lane];
    h1L[wv][lane] = fmaxf(h, 0.0f);
    __syncthreads();

    // g2: 64 -> 32
    if (lane < 32) {
        float v = gb2[lane];
        for (int k = 0; k < 64; ++k) v += h1L[wv][k] * gW2[k * 32 + lane];
        h2L[wv][lane] = fmaxf(v, 0.0f);
    }
    __syncthreads();

    // g3: 32 -> 3, final relu, residual add
    if (lane < 3) {
        float o = gb3[lane];
        for (int m = 0; m < 32; ++m) o += h2L[wv][m] * gW3[m * 3 + lane];
        o = fmaxf(o, 0.0f);
        dst[node * 3 + lane] = o + statesrc[node * 3 + lane];
    }
}

extern "C" void kernel_launch(void* const* d_in, const int* in_sizes, int n_in,
                              void* d_out, int out_size, void* d_ws, size_t ws_size,
                              hipStream_t stream) {
    const float* x   = (const float*)d_in[0];
    // d_in[1..6] = hW1..hb3 : provably unused (delta MLP receives exact zeros)
    const float* fW1 = (const float*)d_in[7];
    const float* fb1 = (const float*)d_in[8];
    const float* fW2 = (const float*)d_in[9];
    const float* fb2 = (const float*)d_in[10];
    const float* fW3 = (const float*)d_in[11];
    const float* fb3 = (const float*)d_in[12];
    const float* gW1 = (const float*)d_in[13];
    const float* gb1 = (const float*)d_in[14];
    const float* gW2 = (const float*)d_in[15];
    const float* gb2 = (const float*)d_in[16];
    const float* gW3 = (const float*)d_in[17];
    const float* gb3 = (const float*)d_in[18];

    char* ws = (char*)d_ws;
    float* state          = (float*)(ws + 0);
    int* cnt              = (int*)(ws + 18432);
    unsigned short* lists = (unsigned short*)(ws + 24576);
    float* phi            = (float*)(ws + 1204224);

    adj_kernel<<<4, 384, 0, stream>>>(x, cnt, lists);

    for (int t = 0; t < 3; ++t) {
        const float* src = (t == 0) ? x : state;
        float* dst = (t == 2) ? (float*)d_out : state;
        phi_kernel<<<96, 256, 0, stream>>>(src,
                                           fW1 + t * 6 * 64, fb1 + t * 64,
                                           fW2 + t * 64 * 128, fb2 + t * 128,
                                           fW3 + t * 128 * 128, fb3 + t * 128,
                                           phi);
        aggg_kernel<<<384, 256, 0, stream>>>(phi, cnt, lists, src,
                                             gW1 + t * 128 * 64, gb1 + t * 64,
                                             gW2 + t * 64 * 32, gb2 + t * 32,
                                             gW3 + t * 32 * 3, gb3 + t * 3,
                                             dst);
    }
}

// Round 2
// 154.507 us; speedup vs baseline: 1.3447x; 1.3447x over previous
//
#include <hip/hip_runtime.h>

#define MNODES 384
#define RTHRESH 0.05f

// ---------------------------------------------------------------------------
// Workspace layout (bytes):
//   state : 1536*3 floats            @ 0        (18432 B)
//   cnt   : 1536 ints                @ 18432    (6144 B)
//   lists : 1536*384 u16             @ 24576    (1179648 B)
//   phi   : 1536*128 floats          @ 1204224  (786432 B)
// total ~1.99 MB
// ---------------------------------------------------------------------------

// Adjacency: wave per node. 384 blocks x 256 (4 waves). Ballot-compacted
// neighbor lists: 6 rounds of 64 j's per wave instead of 384 serial per thread.
__global__ __launch_bounds__(256) void adj_kernel(const float* __restrict__ x,
                                                  int* __restrict__ cnt,
                                                  unsigned short* __restrict__ lists) {
    __shared__ float xs[MNODES * 3];
    const int tid = threadIdx.x;
    const int wv = tid >> 6, lane = tid & 63;
    const int node = blockIdx.x * 4 + wv;        // [0,1536)
    const int n = blockIdx.x / 96;               // batch (96 blocks per batch)
    const int i = node - n * MNODES;

    for (int idx = tid; idx < MNODES * 3; idx += 256)
        xs[idx] = x[n * MNODES * 3 + idx];
    __syncthreads();

    const float xi0 = xs[i * 3], xi1 = xs[i * 3 + 1], xi2 = xs[i * 3 + 2];
    unsigned short* ml = lists + (size_t)node * MNODES;
    int total = 0;
#pragma unroll
    for (int rep = 0; rep < 6; ++rep) {
        const int j = rep * 64 + lane;
        float dx = xs[j * 3] - xi0;
        float dy = xs[j * 3 + 1] - xi1;
        float dz = xs[j * 3 + 2] - xi2;
        // match numpy rounding exactly (no fp-contract): (dx*dx + dy*dy) + dz*dz
        float d2 = __fadd_rn(__fadd_rn(__fmul_rn(dx, dx), __fmul_rn(dy, dy)), __fmul_rn(dz, dz));
        const bool a = d2 < RTHRESH;
        const unsigned long long m = __ballot(a);
        if (a) {
            const int pos = total + __popcll(m & ((1ull << lane) - 1ull));
            ml[pos] = (unsigned short)j;
        }
        total += (int)__popcll(m);
    }
    if (lane == 0) cnt[node] = total;
}

// phi[node][128] = relu(W3^T relu(W2^T relu(W1[3:6]^T s + b1) + b2) + b3)
// Wave per node: 384 blocks x 256 threads = 1536 waves (6 waves/CU).
// Lane kp computes neurons kp and kp+64.
__global__ __launch_bounds__(256) void phi_kernel(const float* __restrict__ state,
                                                  const float* __restrict__ fW1,
                                                  const float* __restrict__ fb1,
                                                  const float* __restrict__ fW2,
                                                  const float* __restrict__ fb2,
                                                  const float* __restrict__ fW3,
                                                  const float* __restrict__ fb3,
                                                  float* __restrict__ phi) {
    __shared__ float H1[4][64];
    __shared__ float H2[4][128];
    const int tid = threadIdx.x;
    const int wv = tid >> 6, lane = tid & 63;
    const int node = blockIdx.x * 4 + wv;

    float sv = 0.0f;
    if (lane < 3) sv = state[node * 3 + lane];
    const float s0 = __shfl(sv, 0), s1 = __shfl(sv, 1), s2 = __shfl(sv, 2);

    // Layer 1 (effective 3->64; rel slot exactly zero so rows 0..2 of fW1 unused)
    float v = fb1[lane];
    v = fmaf(s0, fW1[3 * 64 + lane], v);
    v = fmaf(s1, fW1[4 * 64 + lane], v);
    v = fmaf(s2, fW1[5 * 64 + lane], v);
    H1[wv][lane] = fmaxf(v, 0.0f);
    __syncthreads();

    // Layer 2: 64 -> 128
    float a0 = fb2[lane], a1 = fb2[lane + 64];
#pragma unroll 8
    for (int c = 0; c < 64; ++c) {
        const float h = H1[wv][c];
        a0 = fmaf(h, fW2[c * 128 + lane], a0);
        a1 = fmaf(h, fW2[c * 128 + lane + 64], a1);
    }
    H2[wv][lane] = fmaxf(a0, 0.0f);
    H2[wv][lane + 64] = fmaxf(a1, 0.0f);
    __syncthreads();

    // Layer 3: 128 -> 128, final relu
    float c0 = fb3[lane], c1 = fb3[lane + 64];
#pragma unroll 8
    for (int c = 0; c < 128; ++c) {
        const float h = H2[wv][c];
        c0 = fmaf(h, fW3[c * 128 + lane], c0);
        c1 = fmaf(h, fW3[c * 128 + lane + 64], c1);
    }
    phi[(size_t)node * 128 + lane] = fmaxf(c0, 0.0f);
    phi[(size_t)node * 128 + lane + 64] = fmaxf(c1, 0.0f);
}

// Fused agg (max over neighbor phi) + MLP_g + residual. Wave per node,
// 4-way unrolled neighbor loop for load pipelining.
__global__ __launch_bounds__(256) void aggg_kernel(const float* __restrict__ phi,
                                                   const int* __restrict__ cnt,
                                                   const unsigned short* __restrict__ lists,
                                                   const float* __restrict__ statesrc,
                                                   const float* __restrict__ gW1,
                                                   const float* __restrict__ gb1,
                                                   const float* __restrict__ gW2,
                                                   const float* __restrict__ gb2,
                                                   const float* __restrict__ gW3,
                                                   const float* __restrict__ gb3,
                                                   float* __restrict__ dst) {
    __shared__ float aggL[4][128];
    __shared__ float h1L[4][64];
    __shared__ float h2L[4][32];
    const int tid = threadIdx.x;
    const int wv = tid >> 6, lane = tid & 63;
    // readfirstlane: node is wave-uniform -> cnt/list loads become scalar
    const int node = __builtin_amdgcn_readfirstlane(blockIdx.x * 4 + wv);
    const int nbase = (blockIdx.x / 96) * MNODES;   // batch base node
    const int nc = cnt[node];
    const unsigned short* ml = lists + (size_t)node * MNODES;
    const float* pb = phi + (size_t)nbase * 128;

    // agg: max over neighbors; phi >= 0 and masked entries are 0, so init 0 exact
    float m0 = 0.f, m1 = 0.f, m2 = 0.f, m3 = 0.f;
    float p0 = 0.f, p1 = 0.f, p2 = 0.f, p3 = 0.f;
    int jj = 0;
    for (; jj + 4 <= nc; jj += 4) {
        const int j0 = ml[jj], j1 = ml[jj + 1], j2 = ml[jj + 2], j3 = ml[jj + 3];
        const float* r0 = pb + (size_t)j0 * 128;
        const float* r1 = pb + (size_t)j1 * 128;
        const float* r2 = pb + (size_t)j2 * 128;
        const float* r3 = pb + (size_t)j3 * 128;
        m0 = fmaxf(m0, r0[lane]); p0 = fmaxf(p0, r0[lane + 64]);
        m1 = fmaxf(m1, r1[lane]); p1 = fmaxf(p1, r1[lane + 64]);
        m2 = fmaxf(m2, r2[lane]); p2 = fmaxf(p2, r2[lane + 64]);
        m3 = fmaxf(m3, r3[lane]); p3 = fmaxf(p3, r3[lane + 64]);
    }
    for (; jj < nc; ++jj) {
        const int j = ml[jj];
        const float* r = pb + (size_t)j * 128;
        m0 = fmaxf(m0, r[lane]); p0 = fmaxf(p0, r[lane + 64]);
    }
    aggL[wv][lane] = fmaxf(fmaxf(m0, m1), fmaxf(m2, m3));
    aggL[wv][lane + 64] = fmaxf(fmaxf(p0, p1), fmaxf(p2, p3));
    __syncthreads();

    // g1: 128 -> 64
    float h = gb1[lane];
#pragma unroll 8
    for (int c = 0; c < 128; ++c) h = fmaf(aggL[wv][c], gW1[c * 64 + lane], h);
    h1L[wv][lane] = fmaxf(h, 0.0f);
    __syncthreads();

    // g2: 64 -> 32
    if (lane < 32) {
        float v = gb2[lane];
#pragma unroll 8
        for (int k = 0; k < 64; ++k) v = fmaf(h1L[wv][k], gW2[k * 32 + lane], v);
        h2L[wv][lane] = fmaxf(v, 0.0f);
    }
    __syncthreads();

    // g3: 32 -> 3, final relu, residual add
    if (lane < 3) {
        float o = gb3[lane];
#pragma unroll
        for (int m = 0; m < 32; ++m) o = fmaf(h2L[wv][m], gW3[m * 3 + lane], o);
        dst[node * 3 + lane] = fmaxf(o, 0.0f) + statesrc[node * 3 + lane];
    }
}

extern "C" void kernel_launch(void* const* d_in, const int* in_sizes, int n_in,
                              void* d_out, int out_size, void* d_ws, size_t ws_size,
                              hipStream_t stream) {
    const float* x   = (const float*)d_in[0];
    // d_in[1..6] = hW1..hb3 : provably unused (delta MLP receives exact zeros)
    const float* fW1 = (const float*)d_in[7];
    const float* fb1 = (const float*)d_in[8];
    const float* fW2 = (const float*)d_in[9];
    const float* fb2 = (const float*)d_in[10];
    const float* fW3 = (const float*)d_in[11];
    const float* fb3 = (const float*)d_in[12];
    const float* gW1 = (const float*)d_in[13];
    const float* gb1 = (const float*)d_in[14];
    const float* gW2 = (const float*)d_in[15];
    const float* gb2 = (const float*)d_in[16];
    const float* gW3 = (const float*)d_in[17];
    const float* gb3 = (const float*)d_in[18];

    char* ws = (char*)d_ws;
    float* state          = (float*)(ws + 0);
    int* cnt              = (int*)(ws + 18432);
    unsigned short* lists = (unsigned short*)(ws + 24576);
    float* phi            = (float*)(ws + 1204224);

    adj_kernel<<<384, 256, 0, stream>>>(x, cnt, lists);

    for (int t = 0; t < 3; ++t) {
        const float* src = (t == 0) ? x : state;
        float* dst = (t == 2) ? (float*)d_out : state;
        phi_kernel<<<384, 256, 0, stream>>>(src,
                                            fW1 + t * 6 * 64, fb1 + t * 64,
                                            fW2 + t * 64 * 128, fb2 + t * 128,
                                            fW3 + t * 128 * 128, fb3 + t * 128,
                                            phi);
        aggg_kernel<<<384, 256, 0, stream>>>(phi, cnt, lists, src,
                                             gW1 + t * 128 * 64, gb1 + t * 64,
                                             gW2 + t * 64 * 32, gb2 + t * 32,
                                             gW3 + t * 32 * 3, gb3 + t * 3,
                                             dst);
    }
}